// Round 3
// baseline (614.206 us; speedup 1.0000x reference)
//
#include <hip/hip_runtime.h>
#include <hip/hip_cooperative_groups.h>
#include <hip/hip_bf16.h>

namespace cg = cooperative_groups;

#define BB 128
#define TT 1024
#define ENC_DIM 512
#define QUERY_DIM 1024
#define ATT_DIM 128
#define ATT_FILTERS 32
#define ATT_KERNEL 31
#define TILE_T 128
#define NBLK 512
#define TSPLIT 8
#define TCH (TT / TSPLIT)

__device__ __forceinline__ float tanh_fast(float x) {
    float e = __expf(2.0f * x);
    return 1.0f - 2.0f * __builtin_amdgcn_rcpf(1.0f + e);
}

__global__ __launch_bounds__(256, 4) void k_fused(
    const float* __restrict__ query,   // (B,1024)
    const float* __restrict__ mem,     // (B,T,ENC)
    const float* __restrict__ pm,      // (B,T,128)
    const float* __restrict__ aw,      // (B,T,2)
    const float* __restrict__ Wq,      // (1024,128)
    const float* __restrict__ ck,      // (31,2,32)
    const float* __restrict__ Wloc,    // (32,128)
    const float* __restrict__ v,       // (128)
    float* __restrict__ ctx,           // (B,ENC)   d_out
    float* __restrict__ wts,           // (B,T)     d_out
    float* __restrict__ pqp,           // (2,B,128) ws
    float* __restrict__ energies,      // (B,T)     ws
    float* __restrict__ part)          // (8,B,ENC) ws
{
    cg::grid_group grid = cg::this_grid();
    __shared__ float smem[6400];   // 25.6 KB, reused per phase
    int blk = blockIdx.x;
    int tid = threadIdx.x;

    // ---------- Phase 0: pq partials (blocks 0..255, task = (b, k-half)) ----------
    if (blk < 2 * BB) {
        int b = blk >> 1, h = blk & 1;
        float* q  = smem;         // 512
        float* pp = smem + 512;   // 128
        for (int i = tid; i < 512; i += 256) q[i] = query[b * QUERY_DIM + h * 512 + i];
        __syncthreads();
        int a = tid & 127, ks = tid >> 7;
        const float* w  = Wq + (h * 512 + ks * 256) * ATT_DIM + a;
        const float* qs = q + ks * 256;
        float acc = 0.f;
#pragma unroll 16
        for (int k = 0; k < 256; ++k) acc += qs[k] * w[k * ATT_DIM];
        if (ks) pp[a] = acc;
        __syncthreads();
        if (!ks) pqp[(h * BB + b) * ATT_DIM + a] = acc + pp[a];
    }
    __threadfence();
    grid.sync();

    // ---------- Phase 1: energies (1024 vtasks over NBLK blocks, 2 rounds) ----------
    for (int vb = blk; vb < BB * (TT / TILE_T); vb += NBLK) {
        int b = vb >> 3, t0 = (vb & 7) * TILE_T;
        float* s_aw = smem;              // 316 (pad to 320)
        float* s_ck = smem + 320;        // 1984
        float* s_f  = smem + 320 + 1984; // 4096
        __syncthreads();   // guard smem reuse
        for (int i = tid; i < ATT_KERNEL * 2 * ATT_FILTERS; i += 256) s_ck[i] = ck[i];
        for (int i = tid; i < (TILE_T + 30) * 2; i += 256) {
            int ii = i >> 1, c = i & 1;
            int t = t0 - 15 + ii;
            s_aw[i] = (t >= 0 && t < TT) ? aw[(b * TT + t) * 2 + c] : 0.f;
        }
        __syncthreads();

        {   // conv: filter j per thread, weights in regs
            int j = tid & 31;
            float wk0[ATT_KERNEL], wk1[ATT_KERNEL];
#pragma unroll
            for (int k = 0; k < ATT_KERNEL; ++k) {
                wk0[k] = s_ck[k * 64 + j];
                wk1[k] = s_ck[k * 64 + 32 + j];
            }
            for (int t = tid >> 5; t < TILE_T; t += 8) {
                float acc0 = 0.f, acc1 = 0.f;
#pragma unroll
                for (int k = 0; k < ATT_KERNEL; ++k) {
                    float2 awp = *reinterpret_cast<const float2*>(&s_aw[(t + k) * 2]);
                    acc0 += awp.x * wk0[k];
                    acc1 += awp.y * wk1[k];
                }
                s_f[t * ATT_FILTERS + j] = acc0 + acc1;
            }
        }
        __syncthreads();

        int w = tid >> 6, lane = tid & 63;
        int a0 = lane, a1 = lane + 64;
        float wl0[ATT_FILTERS], wl1[ATT_FILTERS];
#pragma unroll
        for (int j = 0; j < ATT_FILTERS; ++j) {
            wl0[j] = Wloc[j * ATT_DIM + a0];
            wl1[j] = Wloc[j * ATT_DIM + a1];
        }
        float pq0 = pqp[b * ATT_DIM + a0] + pqp[(BB + b) * ATT_DIM + a0];
        float pq1 = pqp[b * ATT_DIM + a1] + pqp[(BB + b) * ATT_DIM + a1];
        float v0 = v[a0], v1 = v[a1];

        const float* pmb = pm + ((long)(b * TT + t0)) * ATT_DIM;
        // distance-2 software pipeline on the pm stream
        float c0 = pmb[w * ATT_DIM + a0],       c1 = pmb[w * ATT_DIM + a1];
        float n0 = pmb[(w + 4) * ATT_DIM + a0], n1 = pmb[(w + 4) * ATT_DIM + a1];
        for (int t = w; t < TILE_T; t += 4) {
            float x0 = pq0 + c0;
            float x1 = pq1 + c1;
            c0 = n0; c1 = n1;
            if (t + 8 < TILE_T) {
                n0 = pmb[(t + 8) * ATT_DIM + a0];
                n1 = pmb[(t + 8) * ATT_DIM + a1];
            }
            const float4* f4 = reinterpret_cast<const float4*>(&s_f[t * ATT_FILTERS]);
#pragma unroll
            for (int j4 = 0; j4 < ATT_FILTERS / 4; ++j4) {
                float4 f = f4[j4];
                x0 += f.x * wl0[4 * j4] + f.y * wl0[4 * j4 + 1] + f.z * wl0[4 * j4 + 2] + f.w * wl0[4 * j4 + 3];
                x1 += f.x * wl1[4 * j4] + f.y * wl1[4 * j4 + 1] + f.z * wl1[4 * j4 + 2] + f.w * wl1[4 * j4 + 3];
            }
            float e = tanh_fast(x0) * v0 + tanh_fast(x1) * v1;
#pragma unroll
            for (int off = 32; off > 0; off >>= 1) e += __shfl_xor(e, off);
            if (lane == 0) energies[b * TT + t0 + t] = e;
        }
    }
    __threadfence();
    grid.sync();

    // ---------- Phase 2: softmax (blocks 0..127, one per row) ----------
    if (blk < BB) {
        int b = blk;
        float* red  = smem;
        float* red2 = smem + 4;
        __syncthreads();   // guard smem reuse
        int w = tid >> 6, lane = tid & 63;
        float4 ev = reinterpret_cast<const float4*>(energies + b * TT)[tid];
        float m = fmaxf(fmaxf(ev.x, ev.y), fmaxf(ev.z, ev.w));
#pragma unroll
        for (int off = 32; off > 0; off >>= 1) m = fmaxf(m, __shfl_xor(m, off));
        if (lane == 0) red[w] = m;
        __syncthreads();
        m = fmaxf(fmaxf(red[0], red[1]), fmaxf(red[2], red[3]));
        float4 x;
        x.x = __expf(ev.x - m); x.y = __expf(ev.y - m);
        x.z = __expf(ev.z - m); x.w = __expf(ev.w - m);
        float s = x.x + x.y + x.z + x.w;
#pragma unroll
        for (int off = 32; off > 0; off >>= 1) s += __shfl_xor(s, off);
        if (lane == 0) red2[w] = s;
        __syncthreads();
        s = red2[0] + red2[1] + red2[2] + red2[3];
        float inv = 1.0f / s;
        x.x *= inv; x.y *= inv; x.z *= inv; x.w *= inv;
        reinterpret_cast<float4*>(wts + b * TT)[tid] = x;
    }
    __threadfence();
    grid.sync();

    // ---------- Phase 3: context partials (1024 vtasks, 2 rounds) ----------
    for (int vb = blk; vb < BB * TSPLIT; vb += NBLK) {
        int b = vb >> 3, s = vb & 7;
        float* sw = smem;          // 128
        float* sr = smem + 128;    // 512
        __syncthreads();   // guard smem reuse
        if (tid < TCH / 4)
            reinterpret_cast<float4*>(sw)[tid] =
                reinterpret_cast<const float4*>(wts + b * TT + s * TCH)[tid];
        __syncthreads();
        int p = tid >> 7, q = tid & 127;
        const float4* m4 = reinterpret_cast<const float4*>(mem + ((long)(b * TT + s * TCH)) * ENC_DIM) + q;
        float4 acc = {0.f, 0.f, 0.f, 0.f};
#pragma unroll 8
        for (int t = p; t < TCH; t += 2) {
            float wt = sw[t];
            float4 mv = m4[(long)t * (ENC_DIM / 4)];
            acc.x += wt * mv.x; acc.y += wt * mv.y;
            acc.z += wt * mv.z; acc.w += wt * mv.w;
        }
        __syncthreads();
        if (p == 1) reinterpret_cast<float4*>(sr)[q] = acc;
        __syncthreads();
        if (p == 0) {
            float4 o = reinterpret_cast<float4*>(sr)[q];
            acc.x += o.x; acc.y += o.y; acc.z += o.z; acc.w += o.w;
            reinterpret_cast<float4*>(part)[(s * BB + b) * (ENC_DIM / 4) + q] = acc;
        }
    }
    __threadfence();
    grid.sync();

    // ---------- Phase 4: reduce partials (blocks 0..255) ----------
    if (blk < 256) {
        int i = blk * 256 + tid;   // 65536 outputs
        float a = 0.f;
#pragma unroll
        for (int s = 0; s < TSPLIT; ++s) a += part[s * BB * ENC_DIM + i];
        ctx[i] = a;
    }
}

extern "C" void kernel_launch(void* const* d_in, const int* in_sizes, int n_in,
                              void* d_out, int out_size, void* d_ws, size_t ws_size,
                              hipStream_t stream) {
    const float* query  = (const float*)d_in[0];
    const float* memory = (const float*)d_in[1];
    const float* pm     = (const float*)d_in[2];
    const float* awc    = (const float*)d_in[3];
    const float* Wq     = (const float*)d_in[4];
    const float* ck     = (const float*)d_in[5];
    const float* Wloc   = (const float*)d_in[6];
    const float* v      = (const float*)d_in[7];

    float* out = (float*)d_out;
    float* ctx = out;                       // (B, ENC_DIM)
    float* wts = out + BB * ENC_DIM;        // (B, T)

    float* pqp      = (float*)d_ws;                 // (2,B,128)
    float* energies = pqp + 2 * BB * ATT_DIM;       // (B,T)
    float* part     = energies + BB * TT;           // (8,B,ENC)

    void* args[] = {
        (void*)&query, (void*)&memory, (void*)&pm, (void*)&awc,
        (void*)&Wq, (void*)&ck, (void*)&Wloc, (void*)&v,
        (void*)&ctx, (void*)&wts, (void*)&pqp, (void*)&energies, (void*)&part
    };
    hipLaunchCooperativeKernel((void*)k_fused, dim3(NBLK), dim3(256), args, 0, stream);
}

// Round 4
// 112.902 us; speedup vs baseline: 5.4402x; 5.4402x over previous
//
#include <hip/hip_runtime.h>
#include <hip/hip_bf16.h>

#define BB 128
#define TT 1024
#define ENC_DIM 512
#define QUERY_DIM 1024
#define ATT_DIM 128
#define ATT_FILTERS 32
#define ATT_KERNEL 31
#define TILE_T 64
#define NTILE (TT / TILE_T)   // 16
#define TSPLIT 16
#define TCH (TT / TSPLIT)     // 64

__device__ __forceinline__ float tanh_fast(float x) {
    float e = __expf(2.0f * x);
    return 1.0f - 2.0f * __builtin_amdgcn_rcpf(1.0f + e);
}

// K1: pq partials. grid (B, 2). pqp[(h*B+b)*128+a] = sum over 512 k.
__global__ __launch_bounds__(256) void k_pq(const float* __restrict__ query,
                                            const float* __restrict__ Wq,
                                            float* __restrict__ pqp) {
    __shared__ float q[512];
    __shared__ float pp[128];
    int b = blockIdx.x, h = blockIdx.y;
    int tid = threadIdx.x, a = tid & 127, ks = tid >> 7;
    for (int i = tid; i < 512; i += 256) q[i] = query[b * QUERY_DIM + h * 512 + i];
    __syncthreads();
    const float* w  = Wq + (h * 512 + ks * 256) * ATT_DIM + a;
    const float* qs = q + ks * 256;
    float acc = 0.f;
#pragma unroll 16
    for (int k = 0; k < 256; ++k) acc += qs[k] * w[k * ATT_DIM];
    if (ks) pp[a] = acc;
    __syncthreads();
    if (!ks) pqp[(h * BB + b) * ATT_DIM + a] = acc + pp[a];
}

// K2: energies[b][t] = tanh(pq + conv(aw)@Wloc + pm) . v
// grid (NTILE, B). Each lane owns a-pair (2*lane, 2*lane+1); pm via float2.
__global__ __launch_bounds__(256, 4) void k_energy(
    const float* __restrict__ aw,    // (B,T,2)
    const float* __restrict__ ck,    // (31,2,32)
    const float* __restrict__ Wloc,  // (32,128)
    const float* __restrict__ pm,    // (B,T,128)
    const float* __restrict__ pqp,   // (2,B,128)
    const float* __restrict__ v,     // (128)
    float* __restrict__ energies)    // (B,T)
{
    __shared__ float s_aw[(TILE_T + 30) * 2];
    __shared__ float s_ck[ATT_KERNEL * 2 * ATT_FILTERS];
    __shared__ float s_f[TILE_T * ATT_FILTERS];

    int b = blockIdx.y;
    int t0 = blockIdx.x * TILE_T;
    int tid = threadIdx.x;

    for (int i = tid; i < ATT_KERNEL * 2 * ATT_FILTERS; i += 256) s_ck[i] = ck[i];
    for (int i = tid; i < (TILE_T + 30) * 2; i += 256) {
        int ii = i >> 1, c = i & 1;
        int t = t0 - 15 + ii;
        s_aw[i] = (t >= 0 && t < TT) ? aw[(b * TT + t) * 2 + c] : 0.f;
    }
    __syncthreads();

    {   // conv: filter j per thread, weights register-cached
        int j = tid & 31;
        float wk0[ATT_KERNEL], wk1[ATT_KERNEL];
#pragma unroll
        for (int k = 0; k < ATT_KERNEL; ++k) {
            wk0[k] = s_ck[k * 64 + j];
            wk1[k] = s_ck[k * 64 + 32 + j];
        }
        for (int t = tid >> 5; t < TILE_T; t += 8) {
            float acc0 = 0.f, acc1 = 0.f;
#pragma unroll
            for (int k = 0; k < ATT_KERNEL; ++k) {
                float2 awp = *reinterpret_cast<const float2*>(&s_aw[(t + k) * 2]);
                acc0 += awp.x * wk0[k];
                acc1 += awp.y * wk1[k];
            }
            s_f[t * ATT_FILTERS + j] = acc0 + acc1;
        }
    }
    __syncthreads();

    int w = tid >> 6, lane = tid & 63;
    int a = lane * 2;

    float2 wl[ATT_FILTERS];
#pragma unroll
    for (int j = 0; j < ATT_FILTERS; ++j)
        wl[j] = *reinterpret_cast<const float2*>(&Wloc[j * ATT_DIM + a]);
    float2 pqA = *reinterpret_cast<const float2*>(&pqp[b * ATT_DIM + a]);
    float2 pqB = *reinterpret_cast<const float2*>(&pqp[(BB + b) * ATT_DIM + a]);
    float pq0 = pqA.x + pqB.x, pq1 = pqA.y + pqB.y;
    float2 vv = *reinterpret_cast<const float2*>(&v[a]);

    const float* pmb = pm + ((long)(b * TT + t0)) * ATT_DIM + a;
    float2 c = *reinterpret_cast<const float2*>(&pmb[w * ATT_DIM]);
    float2 n = *reinterpret_cast<const float2*>(&pmb[(w + 4) * ATT_DIM]);
    for (int t = w; t < TILE_T; t += 4) {
        float x0 = pq0 + c.x;
        float x1 = pq1 + c.y;
        c = n;
        if (t + 8 < TILE_T) n = *reinterpret_cast<const float2*>(&pmb[(t + 8) * ATT_DIM]);
        const float4* f4 = reinterpret_cast<const float4*>(&s_f[t * ATT_FILTERS]);
#pragma unroll
        for (int j4 = 0; j4 < ATT_FILTERS / 4; ++j4) {
            float4 f = f4[j4];
            x0 += f.x * wl[4 * j4].x     + f.y * wl[4 * j4 + 1].x
                + f.z * wl[4 * j4 + 2].x + f.w * wl[4 * j4 + 3].x;
            x1 += f.x * wl[4 * j4].y     + f.y * wl[4 * j4 + 1].y
                + f.z * wl[4 * j4 + 2].y + f.w * wl[4 * j4 + 3].y;
        }
        float e = tanh_fast(x0) * vv.x + tanh_fast(x1) * vv.y;
#pragma unroll
        for (int off = 32; off > 0; off >>= 1) e += __shfl_xor(e, off);
        if (lane == 0) energies[b * TT + t0 + t] = e;
    }
}

// K3: fused softmax + partial context. grid (TSPLIT, B).
__global__ __launch_bounds__(256, 8) void k_ctx(
    const float* __restrict__ energies, // (B,T)
    const float* __restrict__ mem,      // (B,T,ENC)
    float* __restrict__ wts_out,        // (B,T)
    float* __restrict__ part)           // (TSPLIT,B,ENC)
{
    __shared__ float sw[TT];
    __shared__ float sr[ENC_DIM];
    __shared__ float red[4], red2[4];
    int s = blockIdx.x, b = blockIdx.y;
    int tid = threadIdx.x, w = tid >> 6, lane = tid & 63;

    // full-row softmax (redundant per block, identical arithmetic)
    float4 ev = reinterpret_cast<const float4*>(energies + b * TT)[tid];
    float m = fmaxf(fmaxf(ev.x, ev.y), fmaxf(ev.z, ev.w));
#pragma unroll
    for (int off = 32; off > 0; off >>= 1) m = fmaxf(m, __shfl_xor(m, off));
    if (lane == 0) red[w] = m;
    __syncthreads();
    m = fmaxf(fmaxf(red[0], red[1]), fmaxf(red[2], red[3]));
    float4 x;
    x.x = __expf(ev.x - m); x.y = __expf(ev.y - m);
    x.z = __expf(ev.z - m); x.w = __expf(ev.w - m);
    float ssum = x.x + x.y + x.z + x.w;
#pragma unroll
    for (int off = 32; off > 0; off >>= 1) ssum += __shfl_xor(ssum, off);
    if (lane == 0) red2[w] = ssum;
    __syncthreads();
    ssum = red2[0] + red2[1] + red2[2] + red2[3];
    float inv = 1.0f / ssum;
    x.x *= inv; x.y *= inv; x.z *= inv; x.w *= inv;
    reinterpret_cast<float4*>(sw)[tid] = x;
    if ((tid >> 4) == s)   // this block's 64-float chunk of the weights output
        reinterpret_cast<float4*>(wts_out + b * TT)[tid] = x;
    __syncthreads();

    // partial context over this block's t-chunk
    int p = tid >> 7, q = tid & 127;
    const float4* m4 = reinterpret_cast<const float4*>(mem + ((long)(b * TT + s * TCH)) * ENC_DIM) + q;
    float4 acc = {0.f, 0.f, 0.f, 0.f};
#pragma unroll 8
    for (int t = p; t < TCH; t += 2) {
        float wt = sw[s * TCH + t];
        float4 mv = m4[(long)t * (ENC_DIM / 4)];
        acc.x += wt * mv.x; acc.y += wt * mv.y;
        acc.z += wt * mv.z; acc.w += wt * mv.w;
    }
    __syncthreads();
    if (p == 1) reinterpret_cast<float4*>(sr)[q] = acc;
    __syncthreads();
    if (p == 0) {
        float4 o = reinterpret_cast<float4*>(sr)[q];
        acc.x += o.x; acc.y += o.y; acc.z += o.z; acc.w += o.w;
        reinterpret_cast<float4*>(part)[(s * BB + b) * (ENC_DIM / 4) + q] = acc;
    }
}

// K4: ctx[b][d] = sum_s part[s][b][d]
__global__ __launch_bounds__(256) void k_reduce(const float* __restrict__ part,
                                               float* __restrict__ ctx) {
    int i = blockIdx.x * 256 + threadIdx.x;   // 65536 outputs
    float a = 0.f;
#pragma unroll
    for (int s = 0; s < TSPLIT; ++s) a += part[s * BB * ENC_DIM + i];
    ctx[i] = a;
}

extern "C" void kernel_launch(void* const* d_in, const int* in_sizes, int n_in,
                              void* d_out, int out_size, void* d_ws, size_t ws_size,
                              hipStream_t stream) {
    const float* query  = (const float*)d_in[0];
    const float* memory = (const float*)d_in[1];
    const float* pm     = (const float*)d_in[2];
    const float* awc    = (const float*)d_in[3];
    const float* Wq     = (const float*)d_in[4];
    const float* ck     = (const float*)d_in[5];
    const float* Wloc   = (const float*)d_in[6];
    const float* v      = (const float*)d_in[7];

    float* out = (float*)d_out;
    float* ctx = out;                       // (B, ENC_DIM)
    float* wts = out + BB * ENC_DIM;        // (B, T)

    float* pqp      = (float*)d_ws;                 // (2,B,128)
    float* energies = pqp + 2 * BB * ATT_DIM;       // (B,T)
    float* part     = energies + BB * TT;           // (TSPLIT,B,ENC)

    k_pq    <<<dim3(BB, 2),      dim3(256), 0, stream>>>(query, Wq, pqp);
    k_energy<<<dim3(NTILE, BB),  dim3(256), 0, stream>>>(awc, ck, Wloc, pm, pqp, v, energies);
    k_ctx   <<<dim3(TSPLIT, BB), dim3(256), 0, stream>>>(energies, memory, wts, part);
    k_reduce<<<dim3(BB * ENC_DIM / 256), dim3(256), 0, stream>>>(part, ctx);
}

// Round 5
// 103.324 us; speedup vs baseline: 5.9445x; 1.0927x over previous
//
#include <hip/hip_runtime.h>
#include <hip/hip_bf16.h>

#define BB 128
#define TT 1024
#define ENC_DIM 512
#define QUERY_DIM 1024
#define ATT_DIM 128
#define ATT_FILTERS 32
#define ATT_KERNEL 31
#define TILE_T 64
#define NTILE (TT / TILE_T)   // 16
#define TSPLIT 16
#define TCH (TT / TSPLIT)     // 64

using f32x4 = __attribute__((ext_vector_type(4))) float;

__device__ __forceinline__ float tanh_fast(float x) {
    float e = __expf(2.0f * x);
    return 1.0f - 2.0f * __builtin_amdgcn_rcpf(1.0f + e);
}

// K1: pq partials. grid (B, 2). h==1 blocks also zero ctx (stream-ordered
// before k_ctx's atomics).
__global__ __launch_bounds__(256) void k_pq(const float* __restrict__ query,
                                            const float* __restrict__ Wq,
                                            float* __restrict__ pqp,
                                            float* __restrict__ ctx) {
    __shared__ float q[512];
    __shared__ float pp[128];
    int b = blockIdx.x, h = blockIdx.y;
    int tid = threadIdx.x, a = tid & 127, ks = tid >> 7;
    if (h == 1) {
        ctx[b * ENC_DIM + tid] = 0.f;
        ctx[b * ENC_DIM + 256 + tid] = 0.f;
    }
    for (int i = tid; i < 512; i += 256) q[i] = query[b * QUERY_DIM + h * 512 + i];
    __syncthreads();
    const float* w  = Wq + (h * 512 + ks * 256) * ATT_DIM + a;
    const float* qs = q + ks * 256;
    float acc = 0.f;
#pragma unroll 16
    for (int k = 0; k < 256; ++k) acc += qs[k] * w[k * ATT_DIM];
    if (ks) pp[a] = acc;
    __syncthreads();
    if (!ks) pqp[(h * BB + b) * ATT_DIM + a] = acc + pp[a];
}

// K2: energies[b][t] = tanh(pq + conv(aw)@Wloc + pm) . v
// grid (NTILE, B). Lane owns a-pair (2*lane, 2*lane+1); pm 4 rows in flight.
__global__ __launch_bounds__(256, 4) void k_energy(
    const float* __restrict__ aw,    // (B,T,2)
    const float* __restrict__ ck,    // (31,2,32)
    const float* __restrict__ Wloc,  // (32,128)
    const float* __restrict__ pm,    // (B,T,128)
    const float* __restrict__ pqp,   // (2,B,128)
    const float* __restrict__ v,     // (128)
    float* __restrict__ energies)    // (B,T)
{
    __shared__ float s_aw[(TILE_T + 30) * 2];
    __shared__ float s_ck[ATT_KERNEL * 2 * ATT_FILTERS];
    __shared__ float s_f[TILE_T * ATT_FILTERS];

    int b = blockIdx.y;
    int t0 = blockIdx.x * TILE_T;
    int tid = threadIdx.x;

    for (int i = tid; i < ATT_KERNEL * 2 * ATT_FILTERS; i += 256) s_ck[i] = ck[i];
    for (int i = tid; i < (TILE_T + 30) * 2; i += 256) {
        int ii = i >> 1, c = i & 1;
        int t = t0 - 15 + ii;
        s_aw[i] = (t >= 0 && t < TT) ? aw[(b * TT + t) * 2 + c] : 0.f;
    }
    __syncthreads();

    {   // conv: filter j per thread, weights register-cached
        int j = tid & 31;
        float wk0[ATT_KERNEL], wk1[ATT_KERNEL];
#pragma unroll
        for (int k = 0; k < ATT_KERNEL; ++k) {
            wk0[k] = s_ck[k * 64 + j];
            wk1[k] = s_ck[k * 64 + 32 + j];
        }
        for (int t = tid >> 5; t < TILE_T; t += 8) {
            float acc0 = 0.f, acc1 = 0.f;
#pragma unroll
            for (int k = 0; k < ATT_KERNEL; ++k) {
                float2 awp = *reinterpret_cast<const float2*>(&s_aw[(t + k) * 2]);
                acc0 += awp.x * wk0[k];
                acc1 += awp.y * wk1[k];
            }
            s_f[t * ATT_FILTERS + j] = acc0 + acc1;
        }
    }
    __syncthreads();

    int w = tid >> 6, lane = tid & 63;
    int a = lane * 2;

    float2 wl[ATT_FILTERS];
#pragma unroll
    for (int j = 0; j < ATT_FILTERS; ++j)
        wl[j] = *reinterpret_cast<const float2*>(&Wloc[j * ATT_DIM + a]);
    float2 pqA = *reinterpret_cast<const float2*>(&pqp[b * ATT_DIM + a]);
    float2 pqB = *reinterpret_cast<const float2*>(&pqp[(BB + b) * ATT_DIM + a]);
    float pq0 = pqA.x + pqB.x, pq1 = pqA.y + pqB.y;
    float2 vv = *reinterpret_cast<const float2*>(&v[a]);

    const float* pmb = pm + ((long)(b * TT + t0)) * ATT_DIM + a;

    auto process = [&](int t, float2 c) {
        float x0 = pq0 + c.x;
        float x1 = pq1 + c.y;
        const float4* f4 = reinterpret_cast<const float4*>(&s_f[t * ATT_FILTERS]);
#pragma unroll
        for (int j4 = 0; j4 < ATT_FILTERS / 4; ++j4) {
            float4 f = f4[j4];
            x0 += f.x * wl[4 * j4].x     + f.y * wl[4 * j4 + 1].x
                + f.z * wl[4 * j4 + 2].x + f.w * wl[4 * j4 + 3].x;
            x1 += f.x * wl[4 * j4].y     + f.y * wl[4 * j4 + 1].y
                + f.z * wl[4 * j4 + 2].y + f.w * wl[4 * j4 + 3].y;
        }
        float e = tanh_fast(x0) * vv.x + tanh_fast(x1) * vv.y;
#pragma unroll
        for (int off = 32; off > 0; off >>= 1) e += __shfl_xor(e, off);
        if (lane == 0) energies[b * TT + t0 + t] = e;
    };

#pragma unroll
    for (int g = 0; g < 4; ++g) {   // 4 rows in flight per group
        int tg = w + g * 16;
        float2 c0 = *reinterpret_cast<const float2*>(&pmb[(tg)      * ATT_DIM]);
        float2 c1 = *reinterpret_cast<const float2*>(&pmb[(tg + 4)  * ATT_DIM]);
        float2 c2 = *reinterpret_cast<const float2*>(&pmb[(tg + 8)  * ATT_DIM]);
        float2 c3 = *reinterpret_cast<const float2*>(&pmb[(tg + 12) * ATT_DIM]);
        process(tg, c0);
        process(tg + 4, c1);
        process(tg + 8, c2);
        process(tg + 12, c3);
    }
}

// K3: fused softmax + partial context, atomic accumulate into ctx.
// grid (TSPLIT, B).
__global__ __launch_bounds__(256, 8) void k_ctx(
    const float* __restrict__ energies, // (B,T)
    const float* __restrict__ mem,      // (B,T,ENC)
    float* __restrict__ wts_out,        // (B,T)
    float* __restrict__ ctx)            // (B,ENC), zeroed by k_pq
{
    __shared__ float sw[TT];
    __shared__ f32x4 sr[ENC_DIM / 4];
    __shared__ float red[4], red2[4];
    int s = blockIdx.x, b = blockIdx.y;
    int tid = threadIdx.x, w = tid >> 6, lane = tid & 63;

    // full-row softmax (redundant per block, identical arithmetic)
    float4 ev = reinterpret_cast<const float4*>(energies + b * TT)[tid];
    float m = fmaxf(fmaxf(ev.x, ev.y), fmaxf(ev.z, ev.w));
#pragma unroll
    for (int off = 32; off > 0; off >>= 1) m = fmaxf(m, __shfl_xor(m, off));
    if (lane == 0) red[w] = m;
    __syncthreads();
    m = fmaxf(fmaxf(red[0], red[1]), fmaxf(red[2], red[3]));
    float4 x;
    x.x = __expf(ev.x - m); x.y = __expf(ev.y - m);
    x.z = __expf(ev.z - m); x.w = __expf(ev.w - m);
    float ssum = x.x + x.y + x.z + x.w;
#pragma unroll
    for (int off = 32; off > 0; off >>= 1) ssum += __shfl_xor(ssum, off);
    if (lane == 0) red2[w] = ssum;
    __syncthreads();
    ssum = red2[0] + red2[1] + red2[2] + red2[3];
    float inv = 1.0f / ssum;
    x.x *= inv; x.y *= inv; x.z *= inv; x.w *= inv;
    reinterpret_cast<float4*>(sw)[tid] = x;
    if ((tid >> 4) == s)   // this block's 64-float chunk of the weights output
        reinterpret_cast<float4*>(wts_out + b * TT)[tid] = x;
    __syncthreads();

    // partial context over this block's t-chunk (nontemporal: zero-reuse stream)
    int p = tid >> 7, q = tid & 127;
    const f32x4* m4 = reinterpret_cast<const f32x4*>(mem + ((long)(b * TT + s * TCH)) * ENC_DIM) + q;
    f32x4 acc = {0.f, 0.f, 0.f, 0.f};
#pragma unroll 8
    for (int t = p; t < TCH; t += 2) {
        float wt = sw[s * TCH + t];
        f32x4 mv = __builtin_nontemporal_load(&m4[(long)t * (ENC_DIM / 4)]);
        acc += wt * mv;
    }
    __syncthreads();
    if (p == 1) sr[q] = acc;
    __syncthreads();
    if (p == 0) {
        f32x4 o = sr[q];
        acc += o;
        float* dst = ctx + b * ENC_DIM + 4 * q;
        atomicAdd(dst + 0, acc.x);
        atomicAdd(dst + 1, acc.y);
        atomicAdd(dst + 2, acc.z);
        atomicAdd(dst + 3, acc.w);
    }
}

extern "C" void kernel_launch(void* const* d_in, const int* in_sizes, int n_in,
                              void* d_out, int out_size, void* d_ws, size_t ws_size,
                              hipStream_t stream) {
    const float* query  = (const float*)d_in[0];
    const float* memory = (const float*)d_in[1];
    const float* pm     = (const float*)d_in[2];
    const float* awc    = (const float*)d_in[3];
    const float* Wq     = (const float*)d_in[4];
    const float* ck     = (const float*)d_in[5];
    const float* Wloc   = (const float*)d_in[6];
    const float* v      = (const float*)d_in[7];

    float* out = (float*)d_out;
    float* ctx = out;                       // (B, ENC_DIM)
    float* wts = out + BB * ENC_DIM;        // (B, T)

    float* pqp      = (float*)d_ws;                 // (2,B,128)
    float* energies = pqp + 2 * BB * ATT_DIM;       // (B,T)

    k_pq    <<<dim3(BB, 2),      dim3(256), 0, stream>>>(query, Wq, pqp, ctx);
    k_energy<<<dim3(NTILE, BB),  dim3(256), 0, stream>>>(awc, ck, Wloc, pm, pqp, v, energies);
    k_ctx   <<<dim3(TSPLIT, BB), dim3(256), 0, stream>>>(energies, memory, wts, ctx);
}